// Round 1
// baseline (879.456 us; speedup 1.0000x reference)
//
#include <hip/hip_runtime.h>

#define N_NODES 50000

// ---------- degree count: deg[dst] += 1 ----------
__global__ void k_deg(const int* __restrict__ idx, int E, float* __restrict__ deg) {
    int e = blockIdx.x * blockDim.x + threadIdx.x;
    if (e < E) atomicAdd(&deg[idx[E + e]], 1.0f);
}

// ---------- deg -> deg_inv_sqrt (incl. self loop) ----------
__global__ void k_rsqrt(float* __restrict__ deg, int n) {
    int i = blockIdx.x * blockDim.x + threadIdx.x;
    if (i < n) deg[i] = rsqrtf(deg[i] + 1.0f);
}

// ---------- build Wcat[128][128] = [W_mu | W_ls] ----------
__global__ void k_wcat(const float* __restrict__ wmu, const float* __restrict__ wls,
                       float* __restrict__ wcat) {
    int i = blockIdx.x * blockDim.x + threadIdx.x;
    if (i >= 128 * 128) return;
    int k = i >> 7, j = i & 127;
    wcat[i] = (j < 64) ? wmu[k * 64 + j] : wls[k * 64 + (j - 64)];
}

// ---------- C[n,128] = A[n,128] @ W[128,128], fp32 ----------
// block: 256 threads, 64 rows x 128 cols per block; per-thread 8x4 register tile
__global__ __launch_bounds__(256) void k_gemm128(const float* __restrict__ A,
                                                 const float* __restrict__ W,
                                                 float* __restrict__ C, int nrows) {
    __shared__ float Ws[32][128];
    __shared__ float Xs[64][32];
    int t = threadIdx.x;
    int tx = t & 31;   // col group: cols tx*4 .. tx*4+3
    int ty = t >> 5;   // row group: rows ty*8 .. ty*8+7
    int row0 = blockIdx.x * 64;
    float acc[8][4] = {};

    for (int kb = 0; kb < 4; ++kb) {
        // stage W chunk: rows kb*32 .. +31 (4096 floats = 1024 float4)
        const float4* wsrc = (const float4*)(W + (size_t)kb * 32 * 128);
        float4* wdst = (float4*)(&Ws[0][0]);
        for (int i = t; i < 1024; i += 256) wdst[i] = wsrc[i];
        // stage X chunk: 64 rows x 32 k (512 float4)
        for (int j = t; j < 512; j += 256) {
            int r = j >> 3, c4 = j & 7;
            int row = row0 + r;
            float4 v = make_float4(0.f, 0.f, 0.f, 0.f);
            if (row < nrows)
                v = *(const float4*)(A + (size_t)row * 128 + kb * 32 + c4 * 4);
            *(float4*)(&Xs[r][c4 * 4]) = v;
        }
        __syncthreads();

        #pragma unroll
        for (int kq = 0; kq < 8; ++kq) {
            float4 xv[8];
            #pragma unroll
            for (int r = 0; r < 8; ++r)
                xv[r] = *(const float4*)(&Xs[ty * 8 + r][kq * 4]);
            #pragma unroll
            for (int kk = 0; kk < 4; ++kk) {
                float4 w = *(const float4*)(&Ws[kq * 4 + kk][tx * 4]);
                #pragma unroll
                for (int r = 0; r < 8; ++r) {
                    float xs = (kk == 0) ? xv[r].x : (kk == 1) ? xv[r].y
                             : (kk == 2) ? xv[r].z : xv[r].w;
                    acc[r][0] = fmaf(xs, w.x, acc[r][0]);
                    acc[r][1] = fmaf(xs, w.y, acc[r][1]);
                    acc[r][2] = fmaf(xs, w.z, acc[r][2]);
                    acc[r][3] = fmaf(xs, w.w, acc[r][3]);
                }
            }
        }
        __syncthreads();
    }

    #pragma unroll
    for (int r = 0; r < 8; ++r) {
        int row = row0 + ty * 8 + r;
        if (row < nrows)
            *(float4*)(C + (size_t)row * 128 + tx * 4) =
                make_float4(acc[r][0], acc[r][1], acc[r][2], acc[r][3]);
    }
}

// ---------- edge aggregation, full 128 feats: agg[dst] += norm * xw[src] ----------
// one wave (64 lanes) per edge; lane f handles features f and f+64
__global__ __launch_bounds__(256) void k_agg_full(const int* __restrict__ idx, int E,
                                                  const float* __restrict__ dis,
                                                  const float* __restrict__ xw,
                                                  float* __restrict__ agg) {
    int w = (int)((blockIdx.x * (size_t)blockDim.x + threadIdx.x) >> 6);
    int lane = threadIdx.x & 63;
    if (w >= E) return;
    int s = idx[w], d = idx[E + w];
    float nrm = dis[s] * dis[d];
    const float* xr = xw + (size_t)s * 128;
    float* ar = agg + (size_t)d * 128;
    atomicAdd(&ar[lane],      nrm * xr[lane]);
    atomicAdd(&ar[lane + 64], nrm * xr[lane + 64]);
}

// ---------- edge aggregation, split into mu (f<64) / logstd (f>=64) halves of out ----------
__global__ __launch_bounds__(256) void k_agg_split(const int* __restrict__ idx, int E,
                                                   const float* __restrict__ dis,
                                                   const float* __restrict__ hw,
                                                   float* __restrict__ out) {
    int w = (int)((blockIdx.x * (size_t)blockDim.x + threadIdx.x) >> 6);
    int lane = threadIdx.x & 63;
    if (w >= E) return;
    int s = idx[w], d = idx[E + w];
    float nrm = dis[s] * dis[d];
    const float* xr = hw + (size_t)s * 128;
    atomicAdd(&out[(size_t)d * 64 + lane],                          nrm * xr[lane]);
    atomicAdd(&out[(size_t)N_NODES * 64 + (size_t)d * 64 + lane],   nrm * xr[lane + 64]);
}

// ---------- layer1 epilogue: h = relu(agg + xw*dis^2 + b1), in place on agg ----------
__global__ void k_h(const float* __restrict__ xw, const float* __restrict__ dis,
                    const float* __restrict__ b1, float* __restrict__ agg) {
    int i = blockIdx.x * blockDim.x + threadIdx.x;
    long base = (long)i * 4;
    if (base >= (long)N_NODES * 128) return;
    int row = (int)(base >> 7);
    int col = (int)(base & 127);
    float d2 = dis[row] * dis[row];
    float4 a  = *(float4*)(agg + base);
    float4 xv = *(const float4*)(xw + base);
    float4 bb = *(const float4*)(b1 + col);
    a.x = fmaxf(fmaf(xv.x, d2, a.x) + bb.x, 0.f);
    a.y = fmaxf(fmaf(xv.y, d2, a.y) + bb.y, 0.f);
    a.z = fmaxf(fmaf(xv.z, d2, a.z) + bb.z, 0.f);
    a.w = fmaxf(fmaf(xv.w, d2, a.w) + bb.w, 0.f);
    *(float4*)(agg + base) = a;
}

// ---------- output epilogue: add self-loop + bias to both halves, in place ----------
__global__ void k_out(float* __restrict__ out, const float* __restrict__ hw,
                      const float* __restrict__ dis, const float* __restrict__ bmu,
                      const float* __restrict__ bls) {
    int i = blockIdx.x * blockDim.x + threadIdx.x;
    long base = (long)i * 4;
    if (base >= (long)N_NODES * 64) return;
    int row = (int)(base >> 6);
    int col = (int)(base & 63);
    float d2 = dis[row] * dis[row];

    float4 o1 = *(float4*)(out + base);
    float4 h1 = *(const float4*)(hw + (size_t)row * 128 + col);
    float4 bm = *(const float4*)(bmu + col);
    o1.x += fmaf(h1.x, d2, bm.x);
    o1.y += fmaf(h1.y, d2, bm.y);
    o1.z += fmaf(h1.z, d2, bm.z);
    o1.w += fmaf(h1.w, d2, bm.w);
    *(float4*)(out + base) = o1;

    size_t off2 = (size_t)N_NODES * 64 + base;
    float4 o2 = *(float4*)(out + off2);
    float4 h2 = *(const float4*)(hw + (size_t)row * 128 + 64 + col);
    float4 bl = *(const float4*)(bls + col);
    o2.x += fmaf(h2.x, d2, bl.x);
    o2.y += fmaf(h2.y, d2, bl.y);
    o2.z += fmaf(h2.z, d2, bl.z);
    o2.w += fmaf(h2.w, d2, bl.w);
    *(float4*)(out + off2) = o2;
}

extern "C" void kernel_launch(void* const* d_in, const int* in_sizes, int n_in,
                              void* d_out, int out_size, void* d_ws, size_t ws_size,
                              hipStream_t stream) {
    const float* x   = (const float*)d_in[0];
    const int*   idx = (const int*)d_in[1];
    const float* W1  = (const float*)d_in[2];
    const float* b1  = (const float*)d_in[3];
    const float* Wmu = (const float*)d_in[4];
    const float* bmu = (const float*)d_in[5];
    const float* Wls = (const float*)d_in[6];
    const float* bls = (const float*)d_in[7];
    int E = in_sizes[1] / 2;
    float* out = (float*)d_out;

    float* ws   = (float*)d_ws;
    float* dis  = ws;                              // N floats (deg -> deg_inv_sqrt)
    float* wcat = ws + 50048;                      // 16384 floats
    float* A    = wcat + 16384;                    // N*128 (xw1, later hw)
    float* B    = A + (size_t)N_NODES * 128;       // N*128 (agg1 -> h)

    // degree + normalization
    hipMemsetAsync(dis, 0, N_NODES * sizeof(float), stream);
    k_deg<<<(E + 255) / 256, 256, 0, stream>>>(idx, E, dis);
    k_rsqrt<<<(N_NODES + 255) / 256, 256, 0, stream>>>(dis, N_NODES);

    // layer 1: xw1 = x @ W1
    k_gemm128<<<(N_NODES + 63) / 64, 256, 0, stream>>>(x, W1, A, N_NODES);
    hipMemsetAsync(B, 0, (size_t)N_NODES * 128 * sizeof(float), stream);
    {
        size_t waves = (size_t)E;
        int blocks = (int)((waves * 64 + 255) / 256);
        k_agg_full<<<blocks, 256, 0, stream>>>(idx, E, dis, A, B);
    }
    k_h<<<(N_NODES * 128 / 4 + 255) / 256, 256, 0, stream>>>(A, dis, b1, B);

    // layer 2 (mu and logstd fused via concatenated weights)
    k_wcat<<<(16384 + 255) / 256, 256, 0, stream>>>(Wmu, Wls, wcat);
    k_gemm128<<<(N_NODES + 63) / 64, 256, 0, stream>>>(B, wcat, A, N_NODES);
    hipMemsetAsync(out, 0, (size_t)out_size * sizeof(float), stream);
    {
        size_t waves = (size_t)E;
        int blocks = (int)((waves * 64 + 255) / 256);
        k_agg_split<<<blocks, 256, 0, stream>>>(idx, E, dis, A, out);
    }
    k_out<<<(N_NODES * 64 / 4 + 255) / 256, 256, 0, stream>>>(out, A, dis, bmu, bls);
}

// Round 3
// 417.370 us; speedup vs baseline: 2.1071x; 2.1071x over previous
//
#include <hip/hip_runtime.h>

#define N_NODES 50000
#define SCAN_B 1024

// ---------- degree histogram (int) on dst ----------
__global__ void k_deg(const int* __restrict__ idx, int E, int* __restrict__ deg) {
    int e = blockIdx.x * blockDim.x + threadIdx.x;
    if (e < E) atomicAdd(&deg[idx[E + e]], 1);
}

// ---------- dis[i] = rsqrt(deg[i] + 1) ----------
__global__ void k_rsqrt(const int* __restrict__ deg, float* __restrict__ dis, int n) {
    int i = blockIdx.x * blockDim.x + threadIdx.x;
    if (i < n) dis[i] = rsqrtf((float)deg[i] + 1.0f);
}

// ---------- block-level inclusive scan ----------
__global__ __launch_bounds__(SCAN_B) void k_scan1(const int* __restrict__ deg,
                                                  int* __restrict__ part,
                                                  int* __restrict__ bsum, int n) {
    __shared__ int s[SCAN_B];
    int i = blockIdx.x * SCAN_B + threadIdx.x;
    int v = (i < n) ? deg[i] : 0;
    s[threadIdx.x] = v;
    __syncthreads();
    for (int off = 1; off < SCAN_B; off <<= 1) {
        int t = (threadIdx.x >= off) ? s[threadIdx.x - off] : 0;
        __syncthreads();
        s[threadIdx.x] += t;
        __syncthreads();
    }
    if (i < n) part[i] = s[threadIdx.x];
    if (threadIdx.x == SCAN_B - 1) bsum[blockIdx.x] = s[threadIdx.x];
}

// ---------- add block offsets -> rowptr (exclusive, rowptr[0]=0) ----------
__global__ __launch_bounds__(SCAN_B) void k_scan2(const int* __restrict__ part,
                                                  const int* __restrict__ bsum,
                                                  int* __restrict__ rowptr, int n) {
    int i = blockIdx.x * SCAN_B + threadIdx.x;
    if (i >= n) return;
    int off = 0;
    for (int b = 0; b < blockIdx.x; ++b) off += bsum[b];
    rowptr[i + 1] = part[i] + off;
    if (i == 0) rowptr[0] = 0;
}

// ---------- scatter edges into CSR buckets; precompute per-edge norm ----------
__global__ void k_scatter(const int* __restrict__ idx, int E,
                          const int* __restrict__ rowptr, int* __restrict__ cursor,
                          const float* __restrict__ dis,
                          int* __restrict__ esrc, float* __restrict__ enorm) {
    int e = blockIdx.x * blockDim.x + threadIdx.x;
    if (e >= E) return;
    int s = idx[e], d = idx[E + e];
    int pos = rowptr[d] + atomicAdd(&cursor[d], 1);
    esrc[pos] = s;
    enorm[pos] = dis[s] * dis[d];
}

// ---------- build Wcat[128][128] = [W_mu | W_ls] ----------
__global__ void k_wcat(const float* __restrict__ wmu, const float* __restrict__ wls,
                       float* __restrict__ wcat) {
    int i = blockIdx.x * blockDim.x + threadIdx.x;
    if (i >= 128 * 128) return;
    int k = i >> 7, j = i & 127;
    wcat[i] = (j < 64) ? wmu[k * 64 + j] : wls[k * 64 + (j - 64)];
}

// ---------- C[n,128] = A[n,128] @ W[128,128], fp32 ----------
__global__ __launch_bounds__(256) void k_gemm128(const float* __restrict__ A,
                                                 const float* __restrict__ W,
                                                 float* __restrict__ C, int nrows) {
    __shared__ float Ws[32][128];
    __shared__ float Xs[64][32];
    int t = threadIdx.x;
    int tx = t & 31;
    int ty = t >> 5;
    int row0 = blockIdx.x * 64;
    float acc[8][4] = {};

    for (int kb = 0; kb < 4; ++kb) {
        const float4* wsrc = (const float4*)(W + (size_t)kb * 32 * 128);
        float4* wdst = (float4*)(&Ws[0][0]);
        for (int i = t; i < 1024; i += 256) wdst[i] = wsrc[i];
        for (int j = t; j < 512; j += 256) {
            int r = j >> 3, c4 = j & 7;
            int row = row0 + r;
            float4 v = make_float4(0.f, 0.f, 0.f, 0.f);
            if (row < nrows)
                v = *(const float4*)(A + (size_t)row * 128 + kb * 32 + c4 * 4);
            *(float4*)(&Xs[r][c4 * 4]) = v;
        }
        __syncthreads();

        #pragma unroll
        for (int kq = 0; kq < 8; ++kq) {
            float4 xv[8];
            #pragma unroll
            for (int r = 0; r < 8; ++r)
                xv[r] = *(const float4*)(&Xs[ty * 8 + r][kq * 4]);
            #pragma unroll
            for (int kk = 0; kk < 4; ++kk) {
                float4 w = *(const float4*)(&Ws[kq * 4 + kk][tx * 4]);
                #pragma unroll
                for (int r = 0; r < 8; ++r) {
                    float xs = (kk == 0) ? xv[r].x : (kk == 1) ? xv[r].y
                             : (kk == 2) ? xv[r].z : xv[r].w;
                    acc[r][0] = fmaf(xs, w.x, acc[r][0]);
                    acc[r][1] = fmaf(xs, w.y, acc[r][1]);
                    acc[r][2] = fmaf(xs, w.z, acc[r][2]);
                    acc[r][3] = fmaf(xs, w.w, acc[r][3]);
                }
            }
        }
        __syncthreads();
    }

    #pragma unroll
    for (int r = 0; r < 8; ++r) {
        int row = row0 + ty * 8 + r;
        if (row < nrows)
            *(float4*)(C + (size_t)row * 128 + tx * 4) =
                make_float4(acc[r][0], acc[r][1], acc[r][2], acc[r][3]);
    }
}

// ---------- layer1 aggregation (gather) + fused self-loop + bias + relu ----------
// one wave per dst node; lane holds feats {2*lane, 2*lane+1} as float2
__global__ __launch_bounds__(256) void k_agg1(const int* __restrict__ rowptr,
                                              const int* __restrict__ esrc,
                                              const float* __restrict__ enorm,
                                              const float* __restrict__ xw,
                                              const float* __restrict__ dis,
                                              const float* __restrict__ b1,
                                              float* __restrict__ h, int n) {
    int d = blockIdx.x * 4 + (threadIdx.x >> 6);
    int lane = threadIdx.x & 63;
    if (d >= n) return;
    int beg = rowptr[d], end = rowptr[d + 1];
    float ax = 0.f, ay = 0.f;
    for (int e = beg; e < end; ++e) {
        int s = esrc[e];
        float nrm = enorm[e];
        float2 v = *(const float2*)(xw + (size_t)s * 128 + lane * 2);
        ax = fmaf(nrm, v.x, ax);
        ay = fmaf(nrm, v.y, ay);
    }
    float ds = dis[d];
    float d2 = ds * ds;
    float2 sv = *(const float2*)(xw + (size_t)d * 128 + lane * 2);
    float2 bb = *(const float2*)(b1 + lane * 2);
    float2 r;
    r.x = fmaxf(fmaf(d2, sv.x, ax) + bb.x, 0.f);
    r.y = fmaxf(fmaf(d2, sv.y, ay) + bb.y, 0.f);
    *(float2*)(h + (size_t)d * 128 + lane * 2) = r;
}

// ---------- layer2 aggregation + fused self-loop + bias, split mu/logstd ----------
__global__ __launch_bounds__(256) void k_agg2(const int* __restrict__ rowptr,
                                              const int* __restrict__ esrc,
                                              const float* __restrict__ enorm,
                                              const float* __restrict__ hw,
                                              const float* __restrict__ dis,
                                              const float* __restrict__ bmu,
                                              const float* __restrict__ bls,
                                              float* __restrict__ out, int n) {
    int d = blockIdx.x * 4 + (threadIdx.x >> 6);
    int lane = threadIdx.x & 63;
    if (d >= n) return;
    int beg = rowptr[d], end = rowptr[d + 1];
    float ax = 0.f, ay = 0.f;
    for (int e = beg; e < end; ++e) {
        int s = esrc[e];
        float nrm = enorm[e];
        float2 v = *(const float2*)(hw + (size_t)s * 128 + lane * 2);
        ax = fmaf(nrm, v.x, ax);
        ay = fmaf(nrm, v.y, ay);
    }
    float ds = dis[d];
    float d2 = ds * ds;
    float2 sv = *(const float2*)(hw + (size_t)d * 128 + lane * 2);
    float2 bb = (lane < 32) ? *(const float2*)(bmu + lane * 2)
                            : *(const float2*)(bls + (lane - 32) * 2);
    float2 r;
    r.x = fmaf(d2, sv.x, ax) + bb.x;
    r.y = fmaf(d2, sv.y, ay) + bb.y;
    float* op = (lane < 32) ? out + (size_t)d * 64 + lane * 2
                            : out + (size_t)N_NODES * 64 + (size_t)d * 64 + (lane - 32) * 2;
    *(float2*)op = r;
}

extern "C" void kernel_launch(void* const* d_in, const int* in_sizes, int n_in,
                              void* d_out, int out_size, void* d_ws, size_t ws_size,
                              hipStream_t stream) {
    const float* x   = (const float*)d_in[0];
    const int*   idx = (const int*)d_in[1];
    const float* W1  = (const float*)d_in[2];
    const float* b1  = (const float*)d_in[3];
    const float* Wmu = (const float*)d_in[4];
    const float* bmu = (const float*)d_in[5];
    const float* Wls = (const float*)d_in[6];
    const float* bls = (const float*)d_in[7];
    int E = in_sizes[1] / 2;
    float* out = (float*)d_out;

    // workspace layout (4-byte elements)
    char* ws = (char*)d_ws;
    int*   degi   = (int*)ws;                            // N
    float* dis    = (float*)(ws + 50048u * 4);           // N
    int*   part   = (int*)(ws + 100096u * 4);            // N (scan partials)
    int*   rowptr = (int*)(ws + 150144u * 4);            // N+1
    int*   bsum   = (int*)(ws + 200208u * 4);            // 64
    int*   cursor = (int*)(ws + 200272u * 4);            // N
    int*   esrc   = (int*)(ws + 250320u * 4);            // E
    float* enorm  = (float*)(ws + (250320u + (size_t)E) * 4);        // E
    float* wcat   = (float*)(ws + (250320u + 2u * (size_t)E) * 4);   // 16384
    float* A      = (float*)(ws + (250320u + 2u * (size_t)E + 16384u) * 4);  // N*128
    float* B      = A + (size_t)N_NODES * 128;                       // N*128

    int nb = (N_NODES + SCAN_B - 1) / SCAN_B;

    // ---- CSR build ----
    hipMemsetAsync(degi, 0, N_NODES * sizeof(int), stream);
    hipMemsetAsync(cursor, 0, N_NODES * sizeof(int), stream);
    k_deg<<<(E + 255) / 256, 256, 0, stream>>>(idx, E, degi);
    k_rsqrt<<<(N_NODES + 255) / 256, 256, 0, stream>>>(degi, dis, N_NODES);
    k_scan1<<<nb, SCAN_B, 0, stream>>>(degi, part, bsum, N_NODES);
    k_scan2<<<nb, SCAN_B, 0, stream>>>(part, bsum, rowptr, N_NODES);
    k_scatter<<<(E + 255) / 256, 256, 0, stream>>>(idx, E, rowptr, cursor, dis, esrc, enorm);

    // ---- layer 1 ----
    k_gemm128<<<(N_NODES + 63) / 64, 256, 0, stream>>>(x, W1, A, N_NODES);
    k_agg1<<<(N_NODES + 3) / 4, 256, 0, stream>>>(rowptr, esrc, enorm, A, dis, b1, B, N_NODES);

    // ---- layer 2 (mu | logstd fused) ----
    k_wcat<<<(16384 + 255) / 256, 256, 0, stream>>>(Wmu, Wls, wcat);
    k_gemm128<<<(N_NODES + 63) / 64, 256, 0, stream>>>(B, wcat, A, N_NODES);
    k_agg2<<<(N_NODES + 3) / 4, 256, 0, stream>>>(rowptr, esrc, enorm, A, dis, bmu, bls, out, N_NODES);
}

// Round 4
// 374.831 us; speedup vs baseline: 2.3463x; 1.1135x over previous
//
#include <hip/hip_runtime.h>

#define N_NODES 50000
#define SCAN_B 1024

// ---------- degree histogram (int) on dst ----------
__global__ void k_deg(const int* __restrict__ idx, int E, int* __restrict__ deg) {
    int e = blockIdx.x * blockDim.x + threadIdx.x;
    if (e < E) atomicAdd(&deg[idx[E + e]], 1);
}

// ---------- dis[i] = rsqrt(deg[i] + 1) ----------
__global__ void k_rsqrt(const int* __restrict__ deg, float* __restrict__ dis, int n) {
    int i = blockIdx.x * blockDim.x + threadIdx.x;
    if (i < n) dis[i] = rsqrtf((float)deg[i] + 1.0f);
}

// ---------- block-level inclusive scan ----------
__global__ __launch_bounds__(SCAN_B) void k_scan1(const int* __restrict__ deg,
                                                  int* __restrict__ part,
                                                  int* __restrict__ bsum, int n) {
    __shared__ int s[SCAN_B];
    int i = blockIdx.x * SCAN_B + threadIdx.x;
    int v = (i < n) ? deg[i] : 0;
    s[threadIdx.x] = v;
    __syncthreads();
    for (int off = 1; off < SCAN_B; off <<= 1) {
        int t = (threadIdx.x >= off) ? s[threadIdx.x - off] : 0;
        __syncthreads();
        s[threadIdx.x] += t;
        __syncthreads();
    }
    if (i < n) part[i] = s[threadIdx.x];
    if (threadIdx.x == SCAN_B - 1) bsum[blockIdx.x] = s[threadIdx.x];
}

// ---------- add block offsets -> rowptr (exclusive, rowptr[0]=0) ----------
__global__ __launch_bounds__(SCAN_B) void k_scan2(const int* __restrict__ part,
                                                  const int* __restrict__ bsum,
                                                  int* __restrict__ rowptr, int n) {
    int i = blockIdx.x * SCAN_B + threadIdx.x;
    if (i >= n) return;
    int off = 0;
    for (int b = 0; b < blockIdx.x; ++b) off += bsum[b];
    rowptr[i + 1] = part[i] + off;
    if (i == 0) rowptr[0] = 0;
}

// ---------- scatter edges into CSR buckets; precompute per-edge norm ----------
__global__ void k_scatter(const int* __restrict__ idx, int E,
                          const int* __restrict__ rowptr, int* __restrict__ cursor,
                          const float* __restrict__ dis,
                          int* __restrict__ esrc, float* __restrict__ enorm) {
    int e = blockIdx.x * blockDim.x + threadIdx.x;
    if (e >= E) return;
    int s = idx[e], d = idx[E + e];
    int pos = rowptr[d] + atomicAdd(&cursor[d], 1);
    esrc[pos] = s;
    enorm[pos] = dis[s] * dis[d];
}

// ---------- build Wcat[128][128] = [W_mu | W_ls] ----------
__global__ void k_wcat(const float* __restrict__ wmu, const float* __restrict__ wls,
                       float* __restrict__ wcat) {
    int i = blockIdx.x * blockDim.x + threadIdx.x;
    if (i >= 128 * 128) return;
    int k = i >> 7, j = i & 127;
    wcat[i] = (j < 64) ? wmu[k * 64 + j] : wls[k * 64 + (j - 64)];
}

// ---------- C[n,128] = A[n,128] @ W[128,128], fp32 ----------
__global__ __launch_bounds__(256) void k_gemm128(const float* __restrict__ A,
                                                 const float* __restrict__ W,
                                                 float* __restrict__ C, int nrows) {
    __shared__ float Ws[32][128];
    __shared__ float Xs[64][32];
    int t = threadIdx.x;
    int tx = t & 31;
    int ty = t >> 5;
    int row0 = blockIdx.x * 64;
    float acc[8][4] = {};

    for (int kb = 0; kb < 4; ++kb) {
        const float4* wsrc = (const float4*)(W + (size_t)kb * 32 * 128);
        float4* wdst = (float4*)(&Ws[0][0]);
        for (int i = t; i < 1024; i += 256) wdst[i] = wsrc[i];
        for (int j = t; j < 512; j += 256) {
            int r = j >> 3, c4 = j & 7;
            int row = row0 + r;
            float4 v = make_float4(0.f, 0.f, 0.f, 0.f);
            if (row < nrows)
                v = *(const float4*)(A + (size_t)row * 128 + kb * 32 + c4 * 4);
            *(float4*)(&Xs[r][c4 * 4]) = v;
        }
        __syncthreads();

        #pragma unroll
        for (int kq = 0; kq < 8; ++kq) {
            float4 xv[8];
            #pragma unroll
            for (int r = 0; r < 8; ++r)
                xv[r] = *(const float4*)(&Xs[ty * 8 + r][kq * 4]);
            #pragma unroll
            for (int kk = 0; kk < 4; ++kk) {
                float4 w = *(const float4*)(&Ws[kq * 4 + kk][tx * 4]);
                #pragma unroll
                for (int r = 0; r < 8; ++r) {
                    float xs = (kk == 0) ? xv[r].x : (kk == 1) ? xv[r].y
                             : (kk == 2) ? xv[r].z : xv[r].w;
                    acc[r][0] = fmaf(xs, w.x, acc[r][0]);
                    acc[r][1] = fmaf(xs, w.y, acc[r][1]);
                    acc[r][2] = fmaf(xs, w.z, acc[r][2]);
                    acc[r][3] = fmaf(xs, w.w, acc[r][3]);
                }
            }
        }
        __syncthreads();
    }

    #pragma unroll
    for (int r = 0; r < 8; ++r) {
        int row = row0 + ty * 8 + r;
        if (row < nrows)
            *(float4*)(C + (size_t)row * 128 + tx * 4) =
                make_float4(acc[r][0], acc[r][1], acc[r][2], acc[r][3]);
    }
}

#define UNR 8

// ---------- layer1 aggregation (gather, 8-deep MLP batches) + self-loop + bias + relu ----------
// one wave per dst node; lane holds feats {2*lane, 2*lane+1}
__global__ __launch_bounds__(256) void k_agg1(const int* __restrict__ rowptr,
                                              const int* __restrict__ esrc,
                                              const float* __restrict__ enorm,
                                              const float* __restrict__ xw,
                                              const float* __restrict__ dis,
                                              const float* __restrict__ b1,
                                              float* __restrict__ h, int n) {
    int d = blockIdx.x * 4 + (threadIdx.x >> 6);
    int lane = threadIdx.x & 63;
    if (d >= n) return;
    int beg = rowptr[d], end = rowptr[d + 1];
    float ax = 0.f, ay = 0.f;
    for (int e = beg; e < end; e += UNR) {
        int sj[UNR]; float nj[UNR];
        #pragma unroll
        for (int j = 0; j < UNR; ++j) {
            int ee = e + j;
            bool ok = ee < end;
            ee = ok ? ee : beg;
            sj[j] = esrc[ee];
            nj[j] = ok ? enorm[ee] : 0.f;
        }
        float2 v[UNR];
        #pragma unroll
        for (int j = 0; j < UNR; ++j)
            v[j] = *(const float2*)(xw + (size_t)sj[j] * 128 + lane * 2);
        #pragma unroll
        for (int j = 0; j < UNR; ++j) {
            ax = fmaf(nj[j], v[j].x, ax);
            ay = fmaf(nj[j], v[j].y, ay);
        }
    }
    float ds = dis[d];
    float d2 = ds * ds;
    float2 sv = *(const float2*)(xw + (size_t)d * 128 + lane * 2);
    float2 bb = *(const float2*)(b1 + lane * 2);
    float2 r;
    r.x = fmaxf(fmaf(d2, sv.x, ax) + bb.x, 0.f);
    r.y = fmaxf(fmaf(d2, sv.y, ay) + bb.y, 0.f);
    *(float2*)(h + (size_t)d * 128 + lane * 2) = r;
}

// ---------- layer2 aggregation + self-loop + bias, split mu/logstd ----------
__global__ __launch_bounds__(256) void k_agg2(const int* __restrict__ rowptr,
                                              const int* __restrict__ esrc,
                                              const float* __restrict__ enorm,
                                              const float* __restrict__ hw,
                                              const float* __restrict__ dis,
                                              const float* __restrict__ bmu,
                                              const float* __restrict__ bls,
                                              float* __restrict__ out, int n) {
    int d = blockIdx.x * 4 + (threadIdx.x >> 6);
    int lane = threadIdx.x & 63;
    if (d >= n) return;
    int beg = rowptr[d], end = rowptr[d + 1];
    float ax = 0.f, ay = 0.f;
    for (int e = beg; e < end; e += UNR) {
        int sj[UNR]; float nj[UNR];
        #pragma unroll
        for (int j = 0; j < UNR; ++j) {
            int ee = e + j;
            bool ok = ee < end;
            ee = ok ? ee : beg;
            sj[j] = esrc[ee];
            nj[j] = ok ? enorm[ee] : 0.f;
        }
        float2 v[UNR];
        #pragma unroll
        for (int j = 0; j < UNR; ++j)
            v[j] = *(const float2*)(hw + (size_t)sj[j] * 128 + lane * 2);
        #pragma unroll
        for (int j = 0; j < UNR; ++j) {
            ax = fmaf(nj[j], v[j].x, ax);
            ay = fmaf(nj[j], v[j].y, ay);
        }
    }
    float ds = dis[d];
    float d2 = ds * ds;
    float2 sv = *(const float2*)(hw + (size_t)d * 128 + lane * 2);
    float2 bb = (lane < 32) ? *(const float2*)(bmu + lane * 2)
                            : *(const float2*)(bls + (lane - 32) * 2);
    float2 r;
    r.x = fmaf(d2, sv.x, ax) + bb.x;
    r.y = fmaf(d2, sv.y, ay) + bb.y;
    float* op = (lane < 32) ? out + (size_t)d * 64 + lane * 2
                            : out + (size_t)N_NODES * 64 + (size_t)d * 64 + (lane - 32) * 2;
    *(float2*)op = r;
}

extern "C" void kernel_launch(void* const* d_in, const int* in_sizes, int n_in,
                              void* d_out, int out_size, void* d_ws, size_t ws_size,
                              hipStream_t stream) {
    const float* x   = (const float*)d_in[0];
    const int*   idx = (const int*)d_in[1];
    const float* W1  = (const float*)d_in[2];
    const float* b1  = (const float*)d_in[3];
    const float* Wmu = (const float*)d_in[4];
    const float* bmu = (const float*)d_in[5];
    const float* Wls = (const float*)d_in[6];
    const float* bls = (const float*)d_in[7];
    int E = in_sizes[1] / 2;
    float* out = (float*)d_out;

    // workspace layout (4-byte elements)
    char* ws = (char*)d_ws;
    int*   degi   = (int*)ws;                            // N
    float* dis    = (float*)(ws + 50048u * 4);           // N
    int*   part   = (int*)(ws + 100096u * 4);            // N (scan partials)
    int*   rowptr = (int*)(ws + 150144u * 4);            // N+1
    int*   bsum   = (int*)(ws + 200208u * 4);            // 64
    int*   cursor = (int*)(ws + 200272u * 4);            // N
    int*   esrc   = (int*)(ws + 250320u * 4);            // E
    float* enorm  = (float*)(ws + (250320u + (size_t)E) * 4);        // E
    float* wcat   = (float*)(ws + (250320u + 2u * (size_t)E) * 4);   // 16384
    float* A      = (float*)(ws + (250320u + 2u * (size_t)E + 16384u) * 4);  // N*128
    float* B      = A + (size_t)N_NODES * 128;                       // N*128

    int nb = (N_NODES + SCAN_B - 1) / SCAN_B;

    // ---- CSR build ----
    hipMemsetAsync(degi, 0, N_NODES * sizeof(int), stream);
    hipMemsetAsync(cursor, 0, N_NODES * sizeof(int), stream);
    k_deg<<<(E + 255) / 256, 256, 0, stream>>>(idx, E, degi);
    k_rsqrt<<<(N_NODES + 255) / 256, 256, 0, stream>>>(degi, dis, N_NODES);
    k_scan1<<<nb, SCAN_B, 0, stream>>>(degi, part, bsum, N_NODES);
    k_scan2<<<nb, SCAN_B, 0, stream>>>(part, bsum, rowptr, N_NODES);
    k_scatter<<<(E + 255) / 256, 256, 0, stream>>>(idx, E, rowptr, cursor, dis, esrc, enorm);

    // ---- layer 1 ----
    k_gemm128<<<(N_NODES + 63) / 64, 256, 0, stream>>>(x, W1, A, N_NODES);
    k_agg1<<<(N_NODES + 3) / 4, 256, 0, stream>>>(rowptr, esrc, enorm, A, dis, b1, B, N_NODES);

    // ---- layer 2 (mu | logstd fused) ----
    k_wcat<<<(16384 + 255) / 256, 256, 0, stream>>>(Wmu, Wls, wcat);
    k_gemm128<<<(N_NODES + 63) / 64, 256, 0, stream>>>(B, wcat, A, N_NODES);
    k_agg2<<<(N_NODES + 3) / 4, 256, 0, stream>>>(rowptr, esrc, enorm, A, dis, bmu, bls, out, N_NODES);
}

// Round 7
// 310.443 us; speedup vs baseline: 2.8329x; 1.2074x over previous
//
#include <hip/hip_runtime.h>
#include <hip/hip_fp16.h>

#define N_NODES 50000
#define SCAN_B 1024
#define UNR 16

// ---------- degree histogram (int) on dst ----------
__global__ void k_deg(const int* __restrict__ idx, int E, int* __restrict__ deg) {
    int e = blockIdx.x * blockDim.x + threadIdx.x;
    if (e < E) atomicAdd(&deg[idx[E + e]], 1);
}

// ---------- dis[i] = rsqrt(deg[i] + 1) ----------
__global__ void k_rsqrt(const int* __restrict__ deg, float* __restrict__ dis, int n) {
    int i = blockIdx.x * blockDim.x + threadIdx.x;
    if (i < n) dis[i] = rsqrtf((float)deg[i] + 1.0f);
}

// ---------- block-level inclusive scan ----------
__global__ __launch_bounds__(SCAN_B) void k_scan1(const int* __restrict__ deg,
                                                  int* __restrict__ part,
                                                  int* __restrict__ bsum, int n) {
    __shared__ int s[SCAN_B];
    int i = blockIdx.x * SCAN_B + threadIdx.x;
    int v = (i < n) ? deg[i] : 0;
    s[threadIdx.x] = v;
    __syncthreads();
    for (int off = 1; off < SCAN_B; off <<= 1) {
        int t = (threadIdx.x >= off) ? s[threadIdx.x - off] : 0;
        __syncthreads();
        s[threadIdx.x] += t;
        __syncthreads();
    }
    if (i < n) part[i] = s[threadIdx.x];
    if (threadIdx.x == SCAN_B - 1) bsum[blockIdx.x] = s[threadIdx.x];
}

// ---------- add block offsets -> rowptr (exclusive, rowptr[0]=0) ----------
__global__ __launch_bounds__(SCAN_B) void k_scan2(const int* __restrict__ part,
                                                  const int* __restrict__ bsum,
                                                  int* __restrict__ rowptr, int n) {
    int i = blockIdx.x * SCAN_B + threadIdx.x;
    if (i >= n) return;
    int off = 0;
    for (int b = 0; b < blockIdx.x; ++b) off += bsum[b];
    rowptr[i + 1] = part[i] + off;
    if (i == 0) rowptr[0] = 0;
}

// ---------- scatter edges into CSR buckets; precompute per-edge norm ----------
__global__ void k_scatter(const int* __restrict__ idx, int E,
                          const int* __restrict__ rowptr, int* __restrict__ cursor,
                          const float* __restrict__ dis,
                          int* __restrict__ esrc, float* __restrict__ enorm) {
    int e = blockIdx.x * blockDim.x + threadIdx.x;
    if (e >= E) return;
    int s = idx[e], d = idx[E + e];
    int pos = rowptr[d] + atomicAdd(&cursor[d], 1);
    esrc[pos] = s;
    enorm[pos] = dis[s] * dis[d];
}

// ---------- build Wcat[128][128] = [W_mu | W_ls] ----------
__global__ void k_wcat(const float* __restrict__ wmu, const float* __restrict__ wls,
                       float* __restrict__ wcat) {
    int i = blockIdx.x * blockDim.x + threadIdx.x;
    if (i >= 128 * 128) return;
    int k = i >> 7, j = i & 127;
    wcat[i] = (j < 64) ? wmu[k * 64 + j] : wls[k * 64 + (j - 64)];
}

// ---------- C16[n,128] = A[n,128] @ W[128,128]; A fp32 or fp16, C fp16 ----------
template <bool IN_HALF>
__global__ __launch_bounds__(256) void k_gemm(const void* __restrict__ Ain,
                                              const float* __restrict__ W,
                                              __half* __restrict__ C, int nrows) {
    __shared__ float Ws[32][128];
    __shared__ float Xs[64][32];
    int t = threadIdx.x;
    int tx = t & 31;
    int ty = t >> 5;
    int row0 = blockIdx.x * 64;
    float acc[8][4] = {};

    for (int kb = 0; kb < 4; ++kb) {
        const float4* wsrc = (const float4*)(W + (size_t)kb * 32 * 128);
        float4* wdst = (float4*)(&Ws[0][0]);
        for (int i = t; i < 1024; i += 256) wdst[i] = wsrc[i];

        if constexpr (!IN_HALF) {
            const float* Af = (const float*)Ain;
            for (int j = t; j < 512; j += 256) {
                int r = j >> 3, c4 = j & 7;
                int row = row0 + r;
                float4 v = make_float4(0.f, 0.f, 0.f, 0.f);
                if (row < nrows)
                    v = *(const float4*)(Af + (size_t)row * 128 + kb * 32 + c4 * 4);
                *(float4*)(&Xs[r][c4 * 4]) = v;
            }
        } else {
            const __half* Ah = (const __half*)Ain;
            // one iter per thread: 8 halves (16B) each
            int r = t >> 2, c8 = (t & 3) * 8;
            int row = row0 + r;
            union { float4 f; __half2 h[4]; } u;
            u.f = make_float4(0.f, 0.f, 0.f, 0.f);
            if (row < nrows)
                u.f = *(const float4*)(Ah + (size_t)row * 128 + kb * 32 + c8);
            float* xp = &Xs[r][c8];
            #pragma unroll
            for (int q = 0; q < 4; ++q) {
                float2 f2 = __half22float2(u.h[q]);
                xp[q * 2] = f2.x;
                xp[q * 2 + 1] = f2.y;
            }
        }
        __syncthreads();

        #pragma unroll
        for (int kq = 0; kq < 8; ++kq) {
            float4 xv[8];
            #pragma unroll
            for (int r = 0; r < 8; ++r)
                xv[r] = *(const float4*)(&Xs[ty * 8 + r][kq * 4]);
            #pragma unroll
            for (int kk = 0; kk < 4; ++kk) {
                float4 w = *(const float4*)(&Ws[kq * 4 + kk][tx * 4]);
                #pragma unroll
                for (int r = 0; r < 8; ++r) {
                    float xs = (kk == 0) ? xv[r].x : (kk == 1) ? xv[r].y
                             : (kk == 2) ? xv[r].z : xv[r].w;
                    acc[r][0] = fmaf(xs, w.x, acc[r][0]);
                    acc[r][1] = fmaf(xs, w.y, acc[r][1]);
                    acc[r][2] = fmaf(xs, w.z, acc[r][2]);
                    acc[r][3] = fmaf(xs, w.w, acc[r][3]);
                }
            }
        }
        __syncthreads();
    }

    #pragma unroll
    for (int r = 0; r < 8; ++r) {
        int row = row0 + ty * 8 + r;
        if (row < nrows) {
            union { float2 f; __half2 h[2]; } o;
            o.h[0] = __float22half2_rn(make_float2(acc[r][0], acc[r][1]));
            o.h[1] = __float22half2_rn(make_float2(acc[r][2], acc[r][3]));
            *(float2*)(C + (size_t)row * 128 + tx * 4) = o.f;
        }
    }
}

// ---------- layer1 aggregation (fp16 gather, 16-deep batches) + self-loop + bias + relu ----------
// one wave per dst node; lane holds feats {2*lane, 2*lane+1}
__global__ __launch_bounds__(256) void k_agg1(const int* __restrict__ rowptr,
                                              const int* __restrict__ esrc,
                                              const float* __restrict__ enorm,
                                              const __half* __restrict__ xw,
                                              const float* __restrict__ dis,
                                              const float* __restrict__ b1,
                                              __half* __restrict__ h, int n) {
    int d = blockIdx.x * 4 + (threadIdx.x >> 6);
    int lane = threadIdx.x & 63;
    if (d >= n) return;
    int beg = rowptr[d], end = rowptr[d + 1];
    float ax = 0.f, ay = 0.f;
    for (int e = beg; e < end; e += UNR) {
        int sj[UNR]; float nj[UNR];
        #pragma unroll
        for (int j = 0; j < UNR; ++j) {
            int ee = e + j;
            bool ok = ee < end;
            ee = ok ? ee : beg;
            sj[j] = esrc[ee];
            nj[j] = ok ? enorm[ee] : 0.f;
        }
        __half2 v[UNR];
        #pragma unroll
        for (int j = 0; j < UNR; ++j)
            v[j] = *(const __half2*)(xw + (size_t)sj[j] * 128 + lane * 2);
        #pragma unroll
        for (int j = 0; j < UNR; ++j) {
            float2 f = __half22float2(v[j]);
            ax = fmaf(nj[j], f.x, ax);
            ay = fmaf(nj[j], f.y, ay);
        }
    }
    float ds = dis[d];
    float d2 = ds * ds;
    float2 sv = __half22float2(*(const __half2*)(xw + (size_t)d * 128 + lane * 2));
    float2 bb = *(const float2*)(b1 + lane * 2);
    float rx = fmaxf(fmaf(d2, sv.x, ax) + bb.x, 0.f);
    float ry = fmaxf(fmaf(d2, sv.y, ay) + bb.y, 0.f);
    *(__half2*)(h + (size_t)d * 128 + lane * 2) = __float22half2_rn(make_float2(rx, ry));
}

// ---------- layer2 aggregation (fp16 gather) + self-loop + bias, split mu/logstd fp32 ----------
__global__ __launch_bounds__(256) void k_agg2(const int* __restrict__ rowptr,
                                              const int* __restrict__ esrc,
                                              const float* __restrict__ enorm,
                                              const __half* __restrict__ hw,
                                              const float* __restrict__ dis,
                                              const float* __restrict__ bmu,
                                              const float* __restrict__ bls,
                                              float* __restrict__ out, int n) {
    int d = blockIdx.x * 4 + (threadIdx.x >> 6);
    int lane = threadIdx.x & 63;
    if (d >= n) return;
    int beg = rowptr[d], end = rowptr[d + 1];
    float ax = 0.f, ay = 0.f;
    for (int e = beg; e < end; e += UNR) {
        int sj[UNR]; float nj[UNR];
        #pragma unroll
        for (int j = 0; j < UNR; ++j) {
            int ee = e + j;
            bool ok = ee < end;
            ee = ok ? ee : beg;
            sj[j] = esrc[ee];
            nj[j] = ok ? enorm[ee] : 0.f;
        }
        __half2 v[UNR];
        #pragma unroll
        for (int j = 0; j < UNR; ++j)
            v[j] = *(const __half2*)(hw + (size_t)sj[j] * 128 + lane * 2);
        #pragma unroll
        for (int j = 0; j < UNR; ++j) {
            float2 f = __half22float2(v[j]);
            ax = fmaf(nj[j], f.x, ax);
            ay = fmaf(nj[j], f.y, ay);
        }
    }
    float ds = dis[d];
    float d2 = ds * ds;
    float2 sv = __half22float2(*(const __half2*)(hw + (size_t)d * 128 + lane * 2));
    float2 bb = (lane < 32) ? *(const float2*)(bmu + lane * 2)
                            : *(const float2*)(bls + (lane - 32) * 2);
    float rx = fmaf(d2, sv.x, ax) + bb.x;
    float ry = fmaf(d2, sv.y, ay) + bb.y;
    float* op = (lane < 32) ? out + (size_t)d * 64 + lane * 2
                            : out + (size_t)N_NODES * 64 + (size_t)d * 64 + (lane - 32) * 2;
    *(float2*)op = make_float2(rx, ry);
}

extern "C" void kernel_launch(void* const* d_in, const int* in_sizes, int n_in,
                              void* d_out, int out_size, void* d_ws, size_t ws_size,
                              hipStream_t stream) {
    const float* x   = (const float*)d_in[0];
    const int*   idx = (const int*)d_in[1];
    const float* W1  = (const float*)d_in[2];
    const float* b1  = (const float*)d_in[3];
    const float* Wmu = (const float*)d_in[4];
    const float* bmu = (const float*)d_in[5];
    const float* Wls = (const float*)d_in[6];
    const float* bls = (const float*)d_in[7];
    int E = in_sizes[1] / 2;
    float* out = (float*)d_out;

    // workspace layout (byte offsets, 16B-aligned chunks)
    char* ws = (char*)d_ws;
    size_t off = 0;
    auto alloc = [&](size_t bytes) { void* p = ws + off; off += (bytes + 15) & ~15ull; return p; };
    int*    degi   = (int*)alloc(N_NODES * 4);
    float*  dis    = (float*)alloc(N_NODES * 4);
    int*    part   = (int*)alloc(N_NODES * 4);
    int*    rowptr = (int*)alloc((N_NODES + 1) * 4);
    int*    bsum   = (int*)alloc(64 * 4);
    int*    cursor = (int*)alloc(N_NODES * 4);
    int*    esrc   = (int*)alloc((size_t)E * 4);
    float*  enorm  = (float*)alloc((size_t)E * 4);
    float*  wcat   = (float*)alloc(16384 * 4);
    __half* A16    = (__half*)alloc((size_t)N_NODES * 128 * 2);   // xw1
    __half* B16    = (__half*)alloc((size_t)N_NODES * 128 * 2);   // h
    __half* C16    = (__half*)alloc((size_t)N_NODES * 128 * 2);   // h @ Wcat

    int nb = (N_NODES + SCAN_B - 1) / SCAN_B;

    // ---- CSR build ----
    hipMemsetAsync(degi, 0, N_NODES * sizeof(int), stream);
    hipMemsetAsync(cursor, 0, N_NODES * sizeof(int), stream);
    k_deg<<<(E + 255) / 256, 256, 0, stream>>>(idx, E, degi);
    k_rsqrt<<<(N_NODES + 255) / 256, 256, 0, stream>>>(degi, dis, N_NODES);
    k_scan1<<<nb, SCAN_B, 0, stream>>>(degi, part, bsum, N_NODES);
    k_scan2<<<nb, SCAN_B, 0, stream>>>(part, bsum, rowptr, N_NODES);
    k_scatter<<<(E + 255) / 256, 256, 0, stream>>>(idx, E, rowptr, cursor, dis, esrc, enorm);

    // ---- layer 1 ----
    k_gemm<false><<<(N_NODES + 63) / 64, 256, 0, stream>>>(x, W1, A16, N_NODES);
    k_agg1<<<(N_NODES + 3) / 4, 256, 0, stream>>>(rowptr, esrc, enorm, A16, dis, b1, B16, N_NODES);

    // ---- layer 2 (mu | logstd fused) ----
    k_wcat<<<(16384 + 255) / 256, 256, 0, stream>>>(Wmu, Wls, wcat);
    k_gemm<true><<<(N_NODES + 63) / 64, 256, 0, stream>>>(B16, wcat, C16, N_NODES);
    k_agg2<<<(N_NODES + 3) / 4, 256, 0, stream>>>(rowptr, esrc, enorm, C16, dis, bmu, bls, out, N_NODES);
}